// Round 21
// baseline (339.452 us; speedup 1.0000x reference)
//
#include <hip/hip_runtime.h>
#include <math.h>

typedef __attribute__((ext_vector_type(8))) short short8;
typedef __attribute__((ext_vector_type(4))) float f32x4;
typedef __attribute__((ext_vector_type(2))) float f32x2;

// ---------------- helpers ----------------
__device__ __forceinline__ float wred_sum(float v) {
#pragma unroll
  for (int off = 32; off; off >>= 1) v += __shfl_xor(v, off, 64);
  return v;
}
__device__ __forceinline__ float b2f(unsigned short u) {
  return __uint_as_float(((unsigned)u) << 16);
}
__device__ __forceinline__ unsigned short f2b(float f) {
  unsigned b = __float_as_uint(f);
  return (unsigned short)((b + 0x7FFFu + ((b >> 16) & 1u)) >> 16);
}
__device__ __forceinline__ unsigned char f2fp8(float v) {
  int pk = __builtin_amdgcn_cvt_pk_fp8_f32(v, v, 0, false);
  return (unsigned char)(pk & 0xFF);
}

// ---- prep: bf16 casts + degree count (rank capture) + action bits + last-block scan ----
__global__ __launch_bounds__(256) void k_prep(
    const float* __restrict__ s0, ushort* __restrict__ d0, int n0,
    const float* __restrict__ s1, ushort* __restrict__ d1, int n1,
    const float* __restrict__ s2, ushort* __restrict__ d2, int n2,
    const float* __restrict__ s3, ushort* __restrict__ d3, int n3,
    const float* __restrict__ s4, ushort* __restrict__ d4, int n4,
    const int* __restrict__ dstv, const float* __restrict__ ea,
    int* __restrict__ cnt_i, float* __restrict__ sum_ea,
    int* __restrict__ rank, int E,
    const int* __restrict__ actions, unsigned* __restrict__ abits,
    int n_act, int castB,
    int* __restrict__ done_ctr, int* __restrict__ row_st, int N) {
  __shared__ int wtot[4];
  __shared__ int lastFlag;
  int b = blockIdx.x, tid = threadIdx.x;
  if (b == 0 && tid < n_act) {
    int a = actions[tid];
    atomicOr(&abits[a >> 5], 1u << (a & 31));
  }
  if (b < castB) {
    int t = (b * 256 + tid) * 4;
    const float* s = 0; ushort* d = 0; int off = t;
    if (off < n0) { s = s0; d = d0; }
    else { off -= n0;
      if (off < n1) { s = s1; d = d1; }
      else { off -= n1;
        if (off < n2) { s = s2; d = d2; }
        else { off -= n2;
          if (off < n3) { s = s3; d = d3; }
          else { off -= n3;
            if (off < n4) { s = s4; d = d4; } } } } }
    if (s) {
      float4 v = *(const float4*)(s + off);
      ushort4 o;
      o.x = f2b(v.x); o.y = f2b(v.y); o.z = f2b(v.z); o.w = f2b(v.w);
      *(ushort4*)(d + off) = o;
    }
  } else {
    int e = (b - castB) * 256 + tid;
    if (e < E) {
      int d = dstv[e];
      int r = atomicAdd(&cnt_i[d], 1);
      atomicAdd(&sum_ea[d], ea[e]);
      __builtin_nontemporal_store(r, &rank[e]);
    }
  }
  __syncthreads();
  if (tid == 0) {
    __threadfence();
    int old = atomicAdd(done_ctr, 1);
    lastFlag = (old == (int)gridDim.x - 1);
  }
  __syncthreads();
  if (lastFlag) {
    __threadfence();                      // acquire: see all counts
    int lane = tid & 63, w = tid >> 6;
    int running = 0;
    for (int base = 0; base < N; base += 256) {
      int i = base + tid;
      int c = (i < N) ? (cnt_i[i] + 1) : 0;
      int inc = c;
#pragma unroll
      for (int off2 = 1; off2 < 64; off2 <<= 1) {
        int u = __shfl_up(inc, off2, 64);
        if (lane >= off2) inc += u;
      }
      if (lane == 63) wtot[w] = inc;
      __syncthreads();
      int woff = 0;
#pragma unroll
      for (int k = 0; k < 4; ++k)
        if (k < w) woff += wtot[k];
      int total = wtot[0] + wtot[1] + wtot[2] + wtot[3];
      int ex = running + woff + inc - c;
      if (i < N) row_st[i] = ex;
      running += total;
      __syncthreads();
    }
    if (tid == 0) row_st[N] = running;
  }
}

// ---------------- layer-1 GEMMs (z=0 fp8-out, z=1 bf16-out) + scatter (z=2) ----
__global__ __launch_bounds__(256) void k_gemm_scatter(const ushort* __restrict__ A,
    const ushort* __restrict__ W0, const float* __restrict__ b0,
    unsigned char* __restrict__ C0fp8,
    const ushort* __restrict__ W1, const float* __restrict__ b1,
    ushort* __restrict__ C1,
    int M, int Nc, int K,
    const int* __restrict__ dstv, const int* __restrict__ srcv,
    const float* __restrict__ ea, const int* __restrict__ cnt_i,
    const float* __restrict__ sum_ea, const int* __restrict__ rank,
    const int* __restrict__ row_st, unsigned* __restrict__ epack,
    int E, int E2) {
  int tid = threadIdx.x;
  if (blockIdx.z == 2) {
    int flat = blockIdx.x * gridDim.y + blockIdx.y;
    int stride = gridDim.x * gridDim.y * 256;
    for (int e = flat * 256 + tid; e < E2; e += stride) {
      int d, sn, rk; float av;
      if (e < E) { d = dstv[e]; sn = srcv[e]; av = ea[e]; rk = rank[e]; }
      else {
        d = e - E; sn = d;
        int c = cnt_i[d];
        av = sum_ea[d] / fmaxf((float)c, 1.0f);
        rk = c;
      }
      int pos = row_st[d] + rk;
      epack[pos] = ((unsigned)f2b(av) << 16) | (unsigned)sn;
    }
    return;
  }
  const ushort* W = blockIdx.z ? W1 : W0;
  const float* bias = blockIdx.z ? b1 : b0;
  int wave = tid >> 6, lane = tid & 63;
  int m0 = blockIdx.x * 64 + wave * 16;
  int n0 = blockIdx.y * 64;
  int r = lane & 15, g = lane >> 4;
  f32x4 acc[4] = {};
  int am = min(m0 + r, M - 1);
  const ushort* Arow = A + (size_t)am * K + g * 8;
  const ushort* Wrow = W + (size_t)(n0 + r) * K + g * 8;
  for (int k0 = 0; k0 < K; k0 += 32) {
    short8 a = *(const short8*)(const void*)(Arow + k0);
#pragma unroll
    for (int c = 0; c < 4; ++c) {
      short8 b = *(const short8*)(const void*)(Wrow + (size_t)c * 16 * K + k0);
      acc[c] = __builtin_amdgcn_mfma_f32_16x16x32_bf16(a, b, acc[c], 0, 0, 0);
    }
  }
#pragma unroll
  for (int c = 0; c < 4; ++c) {
    int gn = n0 + c * 16 + r;
    float bv = bias[gn];
#pragma unroll
    for (int j = 0; j < 4; ++j) {
      int gm = m0 + g * 4 + j;
      if (gm < M) {
        float v = acc[c][j] + bv;
        if (blockIdx.z == 0) C0fp8[(size_t)gm * Nc + gn] = f2fp8(v);
        else                 C1[(size_t)gm * Nc + gn] = f2b(v);
      }
    }
  }
}

// ---------------- layer-2 GEMMs: z=0 fp8-out (xl2), z=1 bf16-out (xr2) ---------
__global__ __launch_bounds__(256) void k_gemm_mfma2(const ushort* __restrict__ A,
    const ushort* __restrict__ W0, const float* __restrict__ b0,
    unsigned char* __restrict__ C0fp8,
    const ushort* __restrict__ W1, const float* __restrict__ b1,
    ushort* __restrict__ C1,
    int M, int Nc, int K) {
  const ushort* W = blockIdx.z ? W1 : W0;
  const float* bias = blockIdx.z ? b1 : b0;
  int wave = threadIdx.x >> 6, lane = threadIdx.x & 63;
  int m0 = blockIdx.x * 64 + wave * 16;
  int n0 = blockIdx.y * 64;
  int r = lane & 15, g = lane >> 4;
  f32x4 acc[4] = {};
  int am = min(m0 + r, M - 1);
  const ushort* Arow = A + (size_t)am * K + g * 8;
  const ushort* Wrow = W + (size_t)(n0 + r) * K + g * 8;
  for (int k0 = 0; k0 < K; k0 += 32) {
    short8 a = *(const short8*)(const void*)(Arow + k0);
#pragma unroll
    for (int c = 0; c < 4; ++c) {
      short8 b = *(const short8*)(const void*)(Wrow + (size_t)c * 16 * K + k0);
      acc[c] = __builtin_amdgcn_mfma_f32_16x16x32_bf16(a, b, acc[c], 0, 0, 0);
    }
  }
#pragma unroll
  for (int c = 0; c < 4; ++c) {
    int gn = n0 + c * 16 + r;
    float bv = bias[gn];
#pragma unroll
    for (int j = 0; j < 4; ++j) {
      int gm = m0 + g * 4 + j;
      if (gm < M) {
        float v = acc[c][j] + bv;
        if (blockIdx.z == 0) C0fp8[(size_t)gm * Nc + gn] = f2fp8(v);
        else                 C1[(size_t)gm * Nc + gn] = f2b(v);
      }
    }
  }
}

// ---------------- layer 1 fused: fp8 xl gather, 2-edge unrolled ----------------
__global__ __launch_bounds__(256) void k_fused1(const unsigned char* __restrict__ xl8,
    const ushort* __restrict__ xr, const unsigned* __restrict__ epack,
    const int* __restrict__ row_st,
    const float* __restrict__ We, const float* __restrict__ att,
    const float* __restrict__ bias, ushort* __restrict__ out, int N) {
  int tid = threadIdx.x;
  int lane = tid & 63;
  int half = lane >> 5, l32 = lane & 31;
  int n = blockIdx.x * 8 + (tid >> 6) * 2 + half;
  if (n >= N) return;
  int c0 = l32 * 8;
  float4 Wa = *(const float4*)(We + c0), Wb = *(const float4*)(We + c0 + 4);
  float4 Aa = *(const float4*)(att + c0), Ab = *(const float4*)(att + c0 + 4);
  float Wev[8] = {Wa.x, Wa.y, Wa.z, Wa.w, Wb.x, Wb.y, Wb.z, Wb.w};
  float atv[8] = {Aa.x, Aa.y, Aa.z, Aa.w, Ab.x, Ab.y, Ab.z, Ab.w};
  short8 xru = *(const short8*)(const void*)(xr + (size_t)n * 256 + c0);
  float xrf[8];
#pragma unroll
  for (int j = 0; j < 8; ++j) xrf[j] = b2f((unsigned short)xru[j]);
  int a = row_st[n], b = row_st[n + 1];
  float m = -INFINITY, den = 0.f;
  float acc[8] = {};
  int i = a;
  for (; i + 1 < b; i += 2) {
    unsigned p0 = epack[i], p1 = epack[i + 1];
    int sn0 = (int)(p0 & 0xFFFFu), sn1 = (int)(p1 & 0xFFFFu);
    float av0 = b2f((unsigned short)(p0 >> 16));
    float av1 = b2f((unsigned short)(p1 >> 16));
    uint2 u0 = *(const uint2*)(const void*)(xl8 + (size_t)sn0 * 256 + c0);
    uint2 u1 = *(const uint2*)(const void*)(xl8 + (size_t)sn1 * 256 + c0);
    float x0[8], x1[8];
    {
      f32x2 da = __builtin_amdgcn_cvt_pk_f32_fp8(u0.x, false);
      f32x2 db = __builtin_amdgcn_cvt_pk_f32_fp8(u0.x, true);
      f32x2 dc = __builtin_amdgcn_cvt_pk_f32_fp8(u0.y, false);
      f32x2 dd = __builtin_amdgcn_cvt_pk_f32_fp8(u0.y, true);
      x0[0] = da[0]; x0[1] = da[1]; x0[2] = db[0]; x0[3] = db[1];
      x0[4] = dc[0]; x0[5] = dc[1]; x0[6] = dd[0]; x0[7] = dd[1];
      da = __builtin_amdgcn_cvt_pk_f32_fp8(u1.x, false);
      db = __builtin_amdgcn_cvt_pk_f32_fp8(u1.x, true);
      dc = __builtin_amdgcn_cvt_pk_f32_fp8(u1.y, false);
      dd = __builtin_amdgcn_cvt_pk_f32_fp8(u1.y, true);
      x1[0] = da[0]; x1[1] = da[1]; x1[2] = db[0]; x1[3] = db[1];
      x1[4] = dc[0]; x1[5] = dc[1]; x1[6] = dd[0]; x1[7] = dd[1];
    }
    float t0 = 0.f, t1 = 0.f;
#pragma unroll
    for (int j = 0; j < 8; ++j) {
      float v0 = x0[j] + xrf[j] + av0 * Wev[j];
      float v1 = x1[j] + xrf[j] + av1 * Wev[j];
      v0 = v0 > 0.f ? v0 : 0.2f * v0;
      v1 = v1 > 0.f ? v1 : 0.2f * v1;
      t0 += atv[j] * v0;
      t1 += atv[j] * v1;
    }
    t0 += __shfl_xor(t0, 1, 8); t1 += __shfl_xor(t1, 1, 8);
    t0 += __shfl_xor(t0, 2, 8); t1 += __shfl_xor(t1, 2, 8);
    t0 += __shfl_xor(t0, 4, 8); t1 += __shfl_xor(t1, 4, 8);
    float tm = fmaxf(t0, t1);
    if (tm > m) {
      float sc = __expf(m - tm);
      m = tm; den *= sc;
#pragma unroll
      for (int j = 0; j < 8; ++j) acc[j] *= sc;
    }
    float e0 = __expf(t0 - m), e1 = __expf(t1 - m);
    den += e0 + e1;
#pragma unroll
    for (int j = 0; j < 8; ++j) acc[j] += e0 * x0[j] + e1 * x1[j];
  }
  if (i < b) {
    unsigned pr = epack[i];
    int sn = (int)(pr & 0xFFFFu);
    float av = b2f((unsigned short)(pr >> 16));
    uint2 u = *(const uint2*)(const void*)(xl8 + (size_t)sn * 256 + c0);
    float x[8];
    f32x2 da = __builtin_amdgcn_cvt_pk_f32_fp8(u.x, false);
    f32x2 db = __builtin_amdgcn_cvt_pk_f32_fp8(u.x, true);
    f32x2 dc = __builtin_amdgcn_cvt_pk_f32_fp8(u.y, false);
    f32x2 dd = __builtin_amdgcn_cvt_pk_f32_fp8(u.y, true);
    x[0] = da[0]; x[1] = da[1]; x[2] = db[0]; x[3] = db[1];
    x[4] = dc[0]; x[5] = dc[1]; x[6] = dd[0]; x[7] = dd[1];
    float t = 0.f;
#pragma unroll
    for (int j = 0; j < 8; ++j) {
      float v = x[j] + xrf[j] + av * Wev[j];
      v = v > 0.f ? v : 0.2f * v;
      t += atv[j] * v;
    }
    t += __shfl_xor(t, 1, 8);
    t += __shfl_xor(t, 2, 8);
    t += __shfl_xor(t, 4, 8);
    if (t > m) {
      float sc = __expf(m - t);
      m = t; den *= sc;
#pragma unroll
      for (int j = 0; j < 8; ++j) acc[j] *= sc;
    }
    float ex = __expf(t - m);
    den += ex;
#pragma unroll
    for (int j = 0; j < 8; ++j) acc[j] += ex * x[j];
  }
  float inv = 1.f / (den + 1e-16f);
  float4 Ba = *(const float4*)(bias + c0), Bb = *(const float4*)(bias + c0 + 4);
  float bv[8] = {Ba.x, Ba.y, Ba.z, Ba.w, Bb.x, Bb.y, Bb.z, Bb.w};
  short8 o;
#pragma unroll
  for (int j = 0; j < 8; ++j) o[j] = (short)f2b(fmaxf(acc[j] * inv + bv[j], 0.f));
  *(short8*)(void*)(out + (size_t)n * 256 + c0) = o;
}

// ---------------- layer 2 fused (fp8 xl2 gather) + global mean pool ------------
__global__ __launch_bounds__(256) void k_fused2(const unsigned char* __restrict__ xl8,
    const ushort* __restrict__ xr, const unsigned* __restrict__ epack,
    const int* __restrict__ row_st,
    const float* __restrict__ We, const float* __restrict__ att,
    const float* __restrict__ bias, float* __restrict__ g_sum, int N) {
  __shared__ float gred[4][64];
  int tid = threadIdx.x;
  int lane = tid & 63, w = tid >> 6;
  int sub = lane >> 3, l8 = lane & 7;
  int n = blockIdx.x * 32 + w * 8 + sub;
  bool valid = n < N;
  int c0 = l8 * 8;
  float4 Wa = *(const float4*)(We + c0), Wb = *(const float4*)(We + c0 + 4);
  float4 Aa = *(const float4*)(att + c0), Ab = *(const float4*)(att + c0 + 4);
  float Wev[8] = {Wa.x, Wa.y, Wa.z, Wa.w, Wb.x, Wb.y, Wb.z, Wb.w};
  float atv[8] = {Aa.x, Aa.y, Aa.z, Aa.w, Ab.x, Ab.y, Ab.z, Ab.w};
  float xrf[8] = {};
  if (valid) {
    short8 xru = *(const short8*)(const void*)(xr + (size_t)n * 64 + c0);
#pragma unroll
    for (int j = 0; j < 8; ++j) xrf[j] = b2f((unsigned short)xru[j]);
  }
  int a = 0, b = 0;
  if (valid) { a = row_st[n]; b = row_st[n + 1]; }
  float m = -INFINITY, den = 0.f;
  float acc[8] = {};
  int i = a;
  for (; i + 1 < b; i += 2) {
    unsigned p0 = epack[i], p1 = epack[i + 1];
    int sn0 = (int)(p0 & 0xFFFFu), sn1 = (int)(p1 & 0xFFFFu);
    float av0 = b2f((unsigned short)(p0 >> 16));
    float av1 = b2f((unsigned short)(p1 >> 16));
    uint2 u0 = *(const uint2*)(const void*)(xl8 + (size_t)sn0 * 64 + c0);
    uint2 u1 = *(const uint2*)(const void*)(xl8 + (size_t)sn1 * 64 + c0);
    float x0[8], x1[8];
    {
      f32x2 da = __builtin_amdgcn_cvt_pk_f32_fp8(u0.x, false);
      f32x2 db = __builtin_amdgcn_cvt_pk_f32_fp8(u0.x, true);
      f32x2 dc = __builtin_amdgcn_cvt_pk_f32_fp8(u0.y, false);
      f32x2 dd = __builtin_amdgcn_cvt_pk_f32_fp8(u0.y, true);
      x0[0] = da[0]; x0[1] = da[1]; x0[2] = db[0]; x0[3] = db[1];
      x0[4] = dc[0]; x0[5] = dc[1]; x0[6] = dd[0]; x0[7] = dd[1];
      da = __builtin_amdgcn_cvt_pk_f32_fp8(u1.x, false);
      db = __builtin_amdgcn_cvt_pk_f32_fp8(u1.x, true);
      dc = __builtin_amdgcn_cvt_pk_f32_fp8(u1.y, false);
      dd = __builtin_amdgcn_cvt_pk_f32_fp8(u1.y, true);
      x1[0] = da[0]; x1[1] = da[1]; x1[2] = db[0]; x1[3] = db[1];
      x1[4] = dc[0]; x1[5] = dc[1]; x1[6] = dd[0]; x1[7] = dd[1];
    }
    float t0 = 0.f, t1 = 0.f;
#pragma unroll
    for (int j = 0; j < 8; ++j) {
      float v0 = x0[j] + xrf[j] + av0 * Wev[j];
      float v1 = x1[j] + xrf[j] + av1 * Wev[j];
      v0 = v0 > 0.f ? v0 : 0.2f * v0;
      v1 = v1 > 0.f ? v1 : 0.2f * v1;
      t0 += atv[j] * v0;
      t1 += atv[j] * v1;
    }
    t0 += __shfl_xor(t0, 1, 8); t1 += __shfl_xor(t1, 1, 8);
    t0 += __shfl_xor(t0, 2, 8); t1 += __shfl_xor(t1, 2, 8);
    t0 += __shfl_xor(t0, 4, 8); t1 += __shfl_xor(t1, 4, 8);
    float tm = fmaxf(t0, t1);
    if (tm > m) {
      float sc = __expf(m - tm);
      m = tm; den *= sc;
#pragma unroll
      for (int j = 0; j < 8; ++j) acc[j] *= sc;
    }
    float e0 = __expf(t0 - m), e1 = __expf(t1 - m);
    den += e0 + e1;
#pragma unroll
    for (int j = 0; j < 8; ++j) acc[j] += e0 * x0[j] + e1 * x1[j];
  }
  if (i < b) {
    unsigned pr = epack[i];
    int sn = (int)(pr & 0xFFFFu);
    float av = b2f((unsigned short)(pr >> 16));
    uint2 u = *(const uint2*)(const void*)(xl8 + (size_t)sn * 64 + c0);
    float x[8];
    f32x2 da = __builtin_amdgcn_cvt_pk_f32_fp8(u.x, false);
    f32x2 db = __builtin_amdgcn_cvt_pk_f32_fp8(u.x, true);
    f32x2 dc = __builtin_amdgcn_cvt_pk_f32_fp8(u.y, false);
    f32x2 dd = __builtin_amdgcn_cvt_pk_f32_fp8(u.y, true);
    x[0] = da[0]; x[1] = da[1]; x[2] = db[0]; x[3] = db[1];
    x[4] = dc[0]; x[5] = dc[1]; x[6] = dd[0]; x[7] = dd[1];
    float t = 0.f;
#pragma unroll
    for (int j = 0; j < 8; ++j) {
      float v = x[j] + xrf[j] + av * Wev[j];
      v = v > 0.f ? v : 0.2f * v;
      t += atv[j] * v;
    }
    t += __shfl_xor(t, 1, 8);
    t += __shfl_xor(t, 2, 8);
    t += __shfl_xor(t, 4, 8);
    if (t > m) {
      float sc = __expf(m - t);
      m = t; den *= sc;
#pragma unroll
      for (int j = 0; j < 8; ++j) acc[j] *= sc;
    }
    float ex = __expf(t - m);
    den += ex;
#pragma unroll
    for (int j = 0; j < 8; ++j) acc[j] += ex * x[j];
  }
  float inv = 1.f / (den + 1e-16f);
  float4 Ba = *(const float4*)(bias + c0), Bb = *(const float4*)(bias + c0 + 4);
  float bv[8] = {Ba.x, Ba.y, Ba.z, Ba.w, Bb.x, Bb.y, Bb.z, Bb.w};
  float vals[8];
#pragma unroll
  for (int j = 0; j < 8; ++j)
    vals[j] = valid ? fmaxf(acc[j] * inv + bv[j], 0.f) : 0.f;
#pragma unroll
  for (int j = 0; j < 8; ++j) {
    float v = vals[j];
    v += __shfl_xor(v, 8, 64);
    v += __shfl_xor(v, 16, 64);
    v += __shfl_xor(v, 32, 64);
    vals[j] = v;
  }
  if (lane < 8) {
#pragma unroll
    for (int j = 0; j < 8; ++j) gred[w][lane * 8 + j] = vals[j];
  }
  __syncthreads();
  if (tid < 64)
    atomicAdd(&g_sum[tid], gred[0][tid] + gred[1][tid] + gred[2][tid] + gred[3][tid]);
}

// ------- masked logits + exp, 2 rows per 4-lane group (ILP), gsum spread -------
__global__ __launch_bounds__(256) void k_logits(const float* __restrict__ g_sum,
    const float* __restrict__ Wp, const float* __restrict__ bp,
    const float* __restrict__ alpha,
    const float* __restrict__ Wf, const float* __restrict__ bf,
    const unsigned* __restrict__ abits, const int* __restrict__ src,
    const int* __restrict__ dst, float* __restrict__ exps,
    float* __restrict__ gsum, float* __restrict__ out,
    int E, int NA, float invN) {
  __shared__ float gs[64];
  __shared__ float wsum[4];
  int tid = threadIdx.x;
  if (tid < 64) gs[tid] = g_sum[tid] * invN;
  __syncthreads();
  if (blockIdx.x == 0 && tid < 64) {
    float t = wred_sum(gs[tid] * Wp[tid]);
    if (tid == 0) {
      float sp = t + bp[0];
      out[NA] = sp > 0.f ? sp : 0.f;
      out[NA + 1] = 1.f / (1.f + __expf(-alpha[0]));
    }
  }
  int j0 = tid & 3;
  int row0 = blockIdx.x * 128 + (tid >> 2);
  int row1 = row0 + 64;
  const float4* g4 = (const float4*)gs;
  float4 gva = g4[j0], gvb = g4[j0 + 4], gvc = g4[j0 + 8], gvd = g4[j0 + 12];
  float ex0 = 0.f, ex1 = 0.f;
  bool r0ok = row0 < NA, r1ok = row1 < NA;
  float acc0 = 0.f, acc1 = 0.f;
  if (r0ok) {
    const float4* wr = (const float4*)(Wf + (size_t)row0 * 64);
    float4 w0 = wr[j0], w1 = wr[j0 + 4], w2 = wr[j0 + 8], w3 = wr[j0 + 12];
    acc0 = w0.x * gva.x + w0.y * gva.y + w0.z * gva.z + w0.w * gva.w
         + w1.x * gvb.x + w1.y * gvb.y + w1.z * gvb.z + w1.w * gvb.w
         + w2.x * gvc.x + w2.y * gvc.y + w2.z * gvc.z + w2.w * gvc.w
         + w3.x * gvd.x + w3.y * gvd.y + w3.z * gvd.z + w3.w * gvd.w;
  }
  if (r1ok) {
    const float4* wr = (const float4*)(Wf + (size_t)row1 * 64);
    float4 w0 = wr[j0], w1 = wr[j0 + 4], w2 = wr[j0 + 8], w3 = wr[j0 + 12];
    acc1 = w0.x * gva.x + w0.y * gva.y + w0.z * gva.z + w0.w * gva.w
         + w1.x * gvb.x + w1.y * gvb.y + w1.z * gvb.z + w1.w * gvb.w
         + w2.x * gvc.x + w2.y * gvc.y + w2.z * gvc.z + w2.w * gvc.w
         + w3.x * gvd.x + w3.y * gvd.y + w3.z * gvd.z + w3.w * gvd.w;
  }
  acc0 += __shfl_xor(acc0, 1, 4); acc1 += __shfl_xor(acc1, 1, 4);
  acc0 += __shfl_xor(acc0, 2, 4); acc1 += __shfl_xor(acc1, 2, 4);
  if (j0 == 0) {
    if (r0ok) {
      bool masked = (abits[row0 >> 5] >> (row0 & 31)) & 1u;
      bool keep = (!masked) && (row0 >= E || src[row0] != dst[row0]);
      ex0 = keep ? __expf(acc0 + bf[row0]) : 0.f;
      exps[row0] = ex0;
    }
    if (r1ok) {
      bool masked = (abits[row1 >> 5] >> (row1 & 31)) & 1u;
      bool keep = (!masked) && (row1 >= E || src[row1] != dst[row1]);
      ex1 = keep ? __expf(acc1 + bf[row1]) : 0.f;
      exps[row1] = ex1;
    }
  }
  float s = wred_sum(ex0 + ex1);
  if ((tid & 63) == 0) wsum[tid >> 6] = s;
  __syncthreads();
  if (tid == 0)
    atomicAdd(&gsum[blockIdx.x & 63],
              wsum[0] + wsum[1] + wsum[2] + wsum[3]);
}

// ---------------- norm: reduce 64 gsum slots in-wave, then scale ---------------
__global__ __launch_bounds__(256) void k_norm(const float* __restrict__ exps,
    const float* __restrict__ gsum, float* __restrict__ out, int NA) {
  int tid = threadIdx.x;
  float total = gsum[tid & 63];
  total = wred_sum(total);
  float inv = 1.f / total;
  int i = (blockIdx.x * 256 + tid) * 4;
  if (i >= NA) return;
  if (i + 3 < NA) {
    float4 v = *(const float4*)(exps + i);
    float4 o;
    o.x = v.x * inv; o.y = v.y * inv; o.z = v.z * inv; o.w = v.w * inv;
    *(float4*)(out + i) = o;
  } else {
    for (int j = i; j < NA; ++j) out[j] = exps[j] * inv;
  }
}

// ---------------- launch ----------------
extern "C" void kernel_launch(void* const* d_in, const int* in_sizes, int n_in,
                              void* d_out, int out_size, void* d_ws, size_t ws_size,
                              hipStream_t stream) {
  const float* x      = (const float*)d_in[0];
  const int*   eidx   = (const int*)d_in[1];
  const float* eattr  = (const float*)d_in[2];
  const int*   actions= (const int*)d_in[3];
  const float* Wl1 = (const float*)d_in[4];
  const float* bl1 = (const float*)d_in[5];
  const float* Wr1 = (const float*)d_in[6];
  const float* br1 = (const float*)d_in[7];
  const float* We1 = (const float*)d_in[8];
  const float* att1= (const float*)d_in[9];
  const float* bias1=(const float*)d_in[10];
  const float* Wl2 = (const float*)d_in[11];
  const float* bl2 = (const float*)d_in[12];
  const float* Wr2 = (const float*)d_in[13];
  const float* br2 = (const float*)d_in[14];
  const float* We2 = (const float*)d_in[15];
  const float* att2= (const float*)d_in[16];
  const float* bias2=(const float*)d_in[17];
  const float* Wf  = (const float*)d_in[18];
  const float* bf  = (const float*)d_in[19];
  const float* Wp  = (const float*)d_in[20];
  const float* bp  = (const float*)d_in[21];
  const float* alpha=(const float*)d_in[22];

  const int F = 128;
  const int N = in_sizes[0] / F;       // 20000
  const int E = in_sizes[2];           // 400000
  const int E2 = E + N;
  const int NA = E + 1;
  const int n_act = in_sizes[3];
  const int* src = eidx;
  const int* dst = eidx + E;

  float* ws = (float*)d_ws;
  size_t p = 0;
  int*      cnt_i    = (int*)(ws + p);      p += (size_t)N;
  float*    sum_ea   = ws + p;              p += (size_t)N;
  float*    g_sum    = ws + p;              p += 64;
  float*    gsum     = ws + p;              p += 64;
  int*      done_ctr = (int*)(ws + p);      p += 64;
  unsigned* abits    = (unsigned*)(ws + p); p += ((size_t)NA + 31) / 32 + 16;
  size_t zero_bytes = p * sizeof(float);
  int*      row_st   = (int*)(ws + p);      p += (size_t)N + 64;
  int*      rank     = (int*)(ws + p);      p += (size_t)E;
  unsigned* epack    = (unsigned*)(ws + p); p += (size_t)E2;
  float*    exps     = ws + p;              p += (size_t)NA + 64;
  unsigned char* xl8 = (unsigned char*)(ws + p); p += (size_t)N * 256 / 4;
  unsigned char* xl28 = (unsigned char*)(ws + p); p += (size_t)N * 64 / 4;
  ushort* ub = (ushort*)(ws + p);
  size_t q = 0;
  ushort* xb   = ub + q; q += (size_t)N * F;
  ushort* wl1b = ub + q; q += (size_t)256 * 128;
  ushort* wr1b = ub + q; q += (size_t)256 * 128;
  ushort* wl2b = ub + q; q += (size_t)64 * 256;
  ushort* wr2b = ub + q; q += (size_t)64 * 256;
  ushort* xr1b = ub + q; q += (size_t)N * 256;
  ushort* h1b  = ub + q; q += (size_t)N * 256;
  ushort* xr2b = ub + q; q += (size_t)N * 64;

  float* out = (float*)d_out;

  hipMemsetAsync(d_ws, 0, zero_bytes, stream);

  // prep: casts + degree count (rank capture) + action bits + last-block scan
  {
    int n0 = N * F, n1 = 256 * 128, n2 = 256 * 128, n3 = 64 * 256, n4 = 64 * 256;
    int tot4 = (n0 + n1 + n2 + n3 + n4) / 4;
    int castB = (tot4 + 255) / 256;
    int cntB = (E + 255) / 256;
    k_prep<<<castB + cntB, 256, 0, stream>>>(
        x, xb, n0, Wl1, wl1b, n1, Wr1, wr1b, n2, Wl2, wl2b, n3, Wr2, wr2b, n4,
        dst, eattr, cnt_i, sum_ea, rank, E, actions, abits, n_act, castB,
        done_ctr, row_st, N);
  }

  // layer-1 GEMMs (fp8 xl out) + atomic-free CSR scatter in one launch
  {
    dim3 g1((N + 63) / 64, 4, 3);
    k_gemm_scatter<<<g1, 256, 0, stream>>>(xb, wl1b, bl1, xl8, wr1b, br1, xr1b,
                                           N, 256, 128,
                                           dst, src, eattr, cnt_i, sum_ea,
                                           rank, row_st, epack, E, E2);
  }
  k_fused1<<<(N + 7) / 8, 256, 0, stream>>>(xl8, xr1b, epack, row_st,
                                            We1, att1, bias1, h1b, N);
  {
    dim3 g2((N + 63) / 64, 1, 2);
    k_gemm_mfma2<<<g2, 256, 0, stream>>>(h1b, wl2b, bl2, xl28, wr2b, br2, xr2b,
                                         N, 64, 256);
  }
  k_fused2<<<(N + 31) / 32, 256, 0, stream>>>(xl28, xr2b, epack, row_st,
                                              We2, att2, bias2, g_sum, N);

  k_logits<<<(NA + 127) / 128, 256, 0, stream>>>(
      g_sum, Wp, bp, alpha, Wf, bf, abits, src, dst,
      exps, gsum, out, E, NA, 1.0f / (float)N);
  int nb4 = (NA + 1023) / 1024;
  k_norm<<<nb4, 256, 0, stream>>>(exps, gsum, out, NA);
}

// Round 22
// 243.012 us; speedup vs baseline: 1.3969x; 1.3969x over previous
//
#include <hip/hip_runtime.h>
#include <math.h>

typedef __attribute__((ext_vector_type(8))) short short8;
typedef __attribute__((ext_vector_type(4))) float f32x4;
typedef __attribute__((ext_vector_type(2))) float f32x2;

// ---------------- helpers ----------------
__device__ __forceinline__ float wred_sum(float v) {
#pragma unroll
  for (int off = 32; off; off >>= 1) v += __shfl_xor(v, off, 64);
  return v;
}
__device__ __forceinline__ float b2f(unsigned short u) {
  return __uint_as_float(((unsigned)u) << 16);
}
__device__ __forceinline__ unsigned short f2b(float f) {
  unsigned b = __float_as_uint(f);
  return (unsigned short)((b + 0x7FFFu + ((b >> 16) & 1u)) >> 16);
}
__device__ __forceinline__ unsigned char f2fp8(float v) {
  int pk = __builtin_amdgcn_cvt_pk_fp8_f32(v, v, 0, false);
  return (unsigned char)(pk & 0xFF);
}

// ---------------- prep: bf16 casts + degree count (rank capture) + aflag -------
__global__ __launch_bounds__(256) void k_prep(
    const float* __restrict__ s0, ushort* __restrict__ d0, int n0,
    const float* __restrict__ s1, ushort* __restrict__ d1, int n1,
    const float* __restrict__ s2, ushort* __restrict__ d2, int n2,
    const float* __restrict__ s3, ushort* __restrict__ d3, int n3,
    const float* __restrict__ s4, ushort* __restrict__ d4, int n4,
    const int* __restrict__ dstv, const float* __restrict__ ea,
    int* __restrict__ cnt_i, float* __restrict__ sum_ea,
    int* __restrict__ rank, int E,
    const int* __restrict__ actions, unsigned char* __restrict__ aflag,
    int n_act, int castB) {
  int b = blockIdx.x, tid = threadIdx.x;
  if (b == 0 && tid < n_act) aflag[actions[tid]] = 1;
  if (b < castB) {
    int t = (b * 256 + tid) * 4;
    const float* s; ushort* d; int off = t;
    if (off < n0) { s = s0; d = d0; }
    else { off -= n0;
      if (off < n1) { s = s1; d = d1; }
      else { off -= n1;
        if (off < n2) { s = s2; d = d2; }
        else { off -= n2;
          if (off < n3) { s = s3; d = d3; }
          else { off -= n3;
            if (off < n4) { s = s4; d = d4; }
            else return; } } } }
    float4 v = *(const float4*)(s + off);
    ushort4 o;
    o.x = f2b(v.x); o.y = f2b(v.y); o.z = f2b(v.z); o.w = f2b(v.w);
    *(ushort4*)(d + off) = o;
    return;
  }
  int e = (b - castB) * 256 + tid;
  if (e >= E) return;
  int d = dstv[e];
  int r = atomicAdd(&cnt_i[d], 1);
  atomicAdd(&sum_ea[d], ea[e]);
  __builtin_nontemporal_store(r, &rank[e]);
}

// ---------------- strip-mined coalesced block scan: row_st[N+1] ----------------
__global__ __launch_bounds__(1024) void k_scan(const int* __restrict__ cnt_i,
    int* __restrict__ row_st, int N) {
  __shared__ int ws[16];
  int tid = threadIdx.x;
  int lane = tid & 63, w = tid >> 6;
  int running = 0;
  for (int base = 0; base < N; base += 1024) {
    int i = base + tid;
    int c = (i < N) ? (cnt_i[i] + 1) : 0;
    int inc = c;
#pragma unroll
    for (int off = 1; off < 64; off <<= 1) {
      int u = __shfl_up(inc, off, 64);
      if (lane >= off) inc += u;
    }
    if (lane == 63) ws[w] = inc;
    __syncthreads();
    if (tid < 16) {
      int s = ws[tid];
#pragma unroll
      for (int off = 1; off < 16; off <<= 1) {
        int u = __shfl_up(s, off, 16);
        if (tid >= off) s += u;
      }
      ws[tid] = s;
    }
    __syncthreads();
    int woff = (w == 0) ? 0 : ws[w - 1];
    int total = ws[15];
    int ex = running + woff + (inc - c);
    if (i < N) row_st[i] = ex;
    running += total;
    __syncthreads();
  }
  if (tid == 0) row_st[N] = running;
}

// ---------------- layer-1 GEMMs (z=0 fp8-out, z=1 bf16-out) + scatter (z=2) ----
__global__ __launch_bounds__(256) void k_gemm_scatter(const ushort* __restrict__ A,
    const ushort* __restrict__ W0, const float* __restrict__ b0,
    unsigned char* __restrict__ C0fp8,
    const ushort* __restrict__ W1, const float* __restrict__ b1,
    ushort* __restrict__ C1,
    int M, int Nc, int K,
    const int* __restrict__ dstv, const int* __restrict__ srcv,
    const float* __restrict__ ea, const int* __restrict__ cnt_i,
    const float* __restrict__ sum_ea, const int* __restrict__ rank,
    const int* __restrict__ row_st, unsigned* __restrict__ epack,
    int E, int E2) {
  int tid = threadIdx.x;
  if (blockIdx.z == 2) {
    int flat = blockIdx.x * gridDim.y + blockIdx.y;
    int stride = gridDim.x * gridDim.y * 256;
    for (int e = flat * 256 + tid; e < E2; e += stride) {
      int d, sn, rk; float av;
      if (e < E) { d = dstv[e]; sn = srcv[e]; av = ea[e]; rk = rank[e]; }
      else {
        d = e - E; sn = d;
        int c = cnt_i[d];
        av = sum_ea[d] / fmaxf((float)c, 1.0f);
        rk = c;
      }
      int pos = row_st[d] + rk;
      epack[pos] = ((unsigned)f2b(av) << 16) | (unsigned)sn;
    }
    return;
  }
  const ushort* W = blockIdx.z ? W1 : W0;
  const float* bias = blockIdx.z ? b1 : b0;
  int wave = tid >> 6, lane = tid & 63;
  int m0 = blockIdx.x * 64 + wave * 16;
  int n0 = blockIdx.y * 64;
  int r = lane & 15, g = lane >> 4;
  f32x4 acc[4] = {};
  int am = min(m0 + r, M - 1);
  const ushort* Arow = A + (size_t)am * K + g * 8;
  const ushort* Wrow = W + (size_t)(n0 + r) * K + g * 8;
  for (int k0 = 0; k0 < K; k0 += 32) {
    short8 a = *(const short8*)(const void*)(Arow + k0);
#pragma unroll
    for (int c = 0; c < 4; ++c) {
      short8 b = *(const short8*)(const void*)(Wrow + (size_t)c * 16 * K + k0);
      acc[c] = __builtin_amdgcn_mfma_f32_16x16x32_bf16(a, b, acc[c], 0, 0, 0);
    }
  }
#pragma unroll
  for (int c = 0; c < 4; ++c) {
    int gn = n0 + c * 16 + r;
    float bv = bias[gn];
#pragma unroll
    for (int j = 0; j < 4; ++j) {
      int gm = m0 + g * 4 + j;
      if (gm < M) {
        float v = acc[c][j] + bv;
        if (blockIdx.z == 0) C0fp8[(size_t)gm * Nc + gn] = f2fp8(v);
        else                 C1[(size_t)gm * Nc + gn] = f2b(v);
      }
    }
  }
}

// ---------------- layer-2 GEMMs: z=0 fp8-out (xl2), z=1 bf16-out (xr2) ---------
__global__ __launch_bounds__(256) void k_gemm_mfma2(const ushort* __restrict__ A,
    const ushort* __restrict__ W0, const float* __restrict__ b0,
    unsigned char* __restrict__ C0fp8,
    const ushort* __restrict__ W1, const float* __restrict__ b1,
    ushort* __restrict__ C1,
    int M, int Nc, int K) {
  const ushort* W = blockIdx.z ? W1 : W0;
  const float* bias = blockIdx.z ? b1 : b0;
  int wave = threadIdx.x >> 6, lane = threadIdx.x & 63;
  int m0 = blockIdx.x * 64 + wave * 16;
  int n0 = blockIdx.y * 64;
  int r = lane & 15, g = lane >> 4;
  f32x4 acc[4] = {};
  int am = min(m0 + r, M - 1);
  const ushort* Arow = A + (size_t)am * K + g * 8;
  const ushort* Wrow = W + (size_t)(n0 + r) * K + g * 8;
  for (int k0 = 0; k0 < K; k0 += 32) {
    short8 a = *(const short8*)(const void*)(Arow + k0);
#pragma unroll
    for (int c = 0; c < 4; ++c) {
      short8 b = *(const short8*)(const void*)(Wrow + (size_t)c * 16 * K + k0);
      acc[c] = __builtin_amdgcn_mfma_f32_16x16x32_bf16(a, b, acc[c], 0, 0, 0);
    }
  }
#pragma unroll
  for (int c = 0; c < 4; ++c) {
    int gn = n0 + c * 16 + r;
    float bv = bias[gn];
#pragma unroll
    for (int j = 0; j < 4; ++j) {
      int gm = m0 + g * 4 + j;
      if (gm < M) {
        float v = acc[c][j] + bv;
        if (blockIdx.z == 0) C0fp8[(size_t)gm * Nc + gn] = f2fp8(v);
        else                 C1[(size_t)gm * Nc + gn] = f2b(v);
      }
    }
  }
}

// ---------------- layer 1 fused: fp8 xl gather, 2-edge unrolled ----------------
__global__ __launch_bounds__(256) void k_fused1(const unsigned char* __restrict__ xl8,
    const ushort* __restrict__ xr, const unsigned* __restrict__ epack,
    const int* __restrict__ row_st,
    const float* __restrict__ We, const float* __restrict__ att,
    const float* __restrict__ bias, ushort* __restrict__ out, int N) {
  int tid = threadIdx.x;
  int lane = tid & 63;
  int half = lane >> 5, l32 = lane & 31;
  int n = blockIdx.x * 8 + (tid >> 6) * 2 + half;
  if (n >= N) return;
  int c0 = l32 * 8;
  float4 Wa = *(const float4*)(We + c0), Wb = *(const float4*)(We + c0 + 4);
  float4 Aa = *(const float4*)(att + c0), Ab = *(const float4*)(att + c0 + 4);
  float Wev[8] = {Wa.x, Wa.y, Wa.z, Wa.w, Wb.x, Wb.y, Wb.z, Wb.w};
  float atv[8] = {Aa.x, Aa.y, Aa.z, Aa.w, Ab.x, Ab.y, Ab.z, Ab.w};
  short8 xru = *(const short8*)(const void*)(xr + (size_t)n * 256 + c0);
  float xrf[8];
#pragma unroll
  for (int j = 0; j < 8; ++j) xrf[j] = b2f((unsigned short)xru[j]);
  int a = row_st[n], b = row_st[n + 1];
  float m = -INFINITY, den = 0.f;
  float acc[8] = {};
  int i = a;
  for (; i + 1 < b; i += 2) {
    unsigned p0 = epack[i], p1 = epack[i + 1];
    int sn0 = (int)(p0 & 0xFFFFu), sn1 = (int)(p1 & 0xFFFFu);
    float av0 = b2f((unsigned short)(p0 >> 16));
    float av1 = b2f((unsigned short)(p1 >> 16));
    uint2 u0 = *(const uint2*)(const void*)(xl8 + (size_t)sn0 * 256 + c0);
    uint2 u1 = *(const uint2*)(const void*)(xl8 + (size_t)sn1 * 256 + c0);
    float x0[8], x1[8];
    {
      f32x2 da = __builtin_amdgcn_cvt_pk_f32_fp8(u0.x, false);
      f32x2 db = __builtin_amdgcn_cvt_pk_f32_fp8(u0.x, true);
      f32x2 dc = __builtin_amdgcn_cvt_pk_f32_fp8(u0.y, false);
      f32x2 dd = __builtin_amdgcn_cvt_pk_f32_fp8(u0.y, true);
      x0[0] = da[0]; x0[1] = da[1]; x0[2] = db[0]; x0[3] = db[1];
      x0[4] = dc[0]; x0[5] = dc[1]; x0[6] = dd[0]; x0[7] = dd[1];
      da = __builtin_amdgcn_cvt_pk_f32_fp8(u1.x, false);
      db = __builtin_amdgcn_cvt_pk_f32_fp8(u1.x, true);
      dc = __builtin_amdgcn_cvt_pk_f32_fp8(u1.y, false);
      dd = __builtin_amdgcn_cvt_pk_f32_fp8(u1.y, true);
      x1[0] = da[0]; x1[1] = da[1]; x1[2] = db[0]; x1[3] = db[1];
      x1[4] = dc[0]; x1[5] = dc[1]; x1[6] = dd[0]; x1[7] = dd[1];
    }
    float t0 = 0.f, t1 = 0.f;
#pragma unroll
    for (int j = 0; j < 8; ++j) {
      float v0 = x0[j] + xrf[j] + av0 * Wev[j];
      float v1 = x1[j] + xrf[j] + av1 * Wev[j];
      v0 = v0 > 0.f ? v0 : 0.2f * v0;
      v1 = v1 > 0.f ? v1 : 0.2f * v1;
      t0 += atv[j] * v0;
      t1 += atv[j] * v1;
    }
    t0 += __shfl_xor(t0, 1, 8); t1 += __shfl_xor(t1, 1, 8);
    t0 += __shfl_xor(t0, 2, 8); t1 += __shfl_xor(t1, 2, 8);
    t0 += __shfl_xor(t0, 4, 8); t1 += __shfl_xor(t1, 4, 8);
    float tm = fmaxf(t0, t1);
    if (tm > m) {
      float sc = __expf(m - tm);
      m = tm; den *= sc;
#pragma unroll
      for (int j = 0; j < 8; ++j) acc[j] *= sc;
    }
    float e0 = __expf(t0 - m), e1 = __expf(t1 - m);
    den += e0 + e1;
#pragma unroll
    for (int j = 0; j < 8; ++j) acc[j] += e0 * x0[j] + e1 * x1[j];
  }
  if (i < b) {
    unsigned pr = epack[i];
    int sn = (int)(pr & 0xFFFFu);
    float av = b2f((unsigned short)(pr >> 16));
    uint2 u = *(const uint2*)(const void*)(xl8 + (size_t)sn * 256 + c0);
    float x[8];
    f32x2 da = __builtin_amdgcn_cvt_pk_f32_fp8(u.x, false);
    f32x2 db = __builtin_amdgcn_cvt_pk_f32_fp8(u.x, true);
    f32x2 dc = __builtin_amdgcn_cvt_pk_f32_fp8(u.y, false);
    f32x2 dd = __builtin_amdgcn_cvt_pk_f32_fp8(u.y, true);
    x[0] = da[0]; x[1] = da[1]; x[2] = db[0]; x[3] = db[1];
    x[4] = dc[0]; x[5] = dc[1]; x[6] = dd[0]; x[7] = dd[1];
    float t = 0.f;
#pragma unroll
    for (int j = 0; j < 8; ++j) {
      float v = x[j] + xrf[j] + av * Wev[j];
      v = v > 0.f ? v : 0.2f * v;
      t += atv[j] * v;
    }
    t += __shfl_xor(t, 1, 8);
    t += __shfl_xor(t, 2, 8);
    t += __shfl_xor(t, 4, 8);
    if (t > m) {
      float sc = __expf(m - t);
      m = t; den *= sc;
#pragma unroll
      for (int j = 0; j < 8; ++j) acc[j] *= sc;
    }
    float ex = __expf(t - m);
    den += ex;
#pragma unroll
    for (int j = 0; j < 8; ++j) acc[j] += ex * x[j];
  }
  float inv = 1.f / (den + 1e-16f);
  float4 Ba = *(const float4*)(bias + c0), Bb = *(const float4*)(bias + c0 + 4);
  float bv[8] = {Ba.x, Ba.y, Ba.z, Ba.w, Bb.x, Bb.y, Bb.z, Bb.w};
  short8 o;
#pragma unroll
  for (int j = 0; j < 8; ++j) o[j] = (short)f2b(fmaxf(acc[j] * inv + bv[j], 0.f));
  *(short8*)(void*)(out + (size_t)n * 256 + c0) = o;
}

// ---------------- layer 2 fused (fp8 xl2 gather) + global mean pool ------------
__global__ __launch_bounds__(256) void k_fused2(const unsigned char* __restrict__ xl8,
    const ushort* __restrict__ xr, const unsigned* __restrict__ epack,
    const int* __restrict__ row_st,
    const float* __restrict__ We, const float* __restrict__ att,
    const float* __restrict__ bias, float* __restrict__ g_sum, int N) {
  __shared__ float gred[4][64];
  int tid = threadIdx.x;
  int lane = tid & 63, w = tid >> 6;
  int sub = lane >> 3, l8 = lane & 7;
  int n = blockIdx.x * 32 + w * 8 + sub;
  bool valid = n < N;
  int c0 = l8 * 8;
  float4 Wa = *(const float4*)(We + c0), Wb = *(const float4*)(We + c0 + 4);
  float4 Aa = *(const float4*)(att + c0), Ab = *(const float4*)(att + c0 + 4);
  float Wev[8] = {Wa.x, Wa.y, Wa.z, Wa.w, Wb.x, Wb.y, Wb.z, Wb.w};
  float atv[8] = {Aa.x, Aa.y, Aa.z, Aa.w, Ab.x, Ab.y, Ab.z, Ab.w};
  float xrf[8] = {};
  if (valid) {
    short8 xru = *(const short8*)(const void*)(xr + (size_t)n * 64 + c0);
#pragma unroll
    for (int j = 0; j < 8; ++j) xrf[j] = b2f((unsigned short)xru[j]);
  }
  int a = 0, b = 0;
  if (valid) { a = row_st[n]; b = row_st[n + 1]; }
  float m = -INFINITY, den = 0.f;
  float acc[8] = {};
  int i = a;
  for (; i + 1 < b; i += 2) {
    unsigned p0 = epack[i], p1 = epack[i + 1];
    int sn0 = (int)(p0 & 0xFFFFu), sn1 = (int)(p1 & 0xFFFFu);
    float av0 = b2f((unsigned short)(p0 >> 16));
    float av1 = b2f((unsigned short)(p1 >> 16));
    uint2 u0 = *(const uint2*)(const void*)(xl8 + (size_t)sn0 * 64 + c0);
    uint2 u1 = *(const uint2*)(const void*)(xl8 + (size_t)sn1 * 64 + c0);
    float x0[8], x1[8];
    {
      f32x2 da = __builtin_amdgcn_cvt_pk_f32_fp8(u0.x, false);
      f32x2 db = __builtin_amdgcn_cvt_pk_f32_fp8(u0.x, true);
      f32x2 dc = __builtin_amdgcn_cvt_pk_f32_fp8(u0.y, false);
      f32x2 dd = __builtin_amdgcn_cvt_pk_f32_fp8(u0.y, true);
      x0[0] = da[0]; x0[1] = da[1]; x0[2] = db[0]; x0[3] = db[1];
      x0[4] = dc[0]; x0[5] = dc[1]; x0[6] = dd[0]; x0[7] = dd[1];
      da = __builtin_amdgcn_cvt_pk_f32_fp8(u1.x, false);
      db = __builtin_amdgcn_cvt_pk_f32_fp8(u1.x, true);
      dc = __builtin_amdgcn_cvt_pk_f32_fp8(u1.y, false);
      dd = __builtin_amdgcn_cvt_pk_f32_fp8(u1.y, true);
      x1[0] = da[0]; x1[1] = da[1]; x1[2] = db[0]; x1[3] = db[1];
      x1[4] = dc[0]; x1[5] = dc[1]; x1[6] = dd[0]; x1[7] = dd[1];
    }
    float t0 = 0.f, t1 = 0.f;
#pragma unroll
    for (int j = 0; j < 8; ++j) {
      float v0 = x0[j] + xrf[j] + av0 * Wev[j];
      float v1 = x1[j] + xrf[j] + av1 * Wev[j];
      v0 = v0 > 0.f ? v0 : 0.2f * v0;
      v1 = v1 > 0.f ? v1 : 0.2f * v1;
      t0 += atv[j] * v0;
      t1 += atv[j] * v1;
    }
    t0 += __shfl_xor(t0, 1, 8); t1 += __shfl_xor(t1, 1, 8);
    t0 += __shfl_xor(t0, 2, 8); t1 += __shfl_xor(t1, 2, 8);
    t0 += __shfl_xor(t0, 4, 8); t1 += __shfl_xor(t1, 4, 8);
    float tm = fmaxf(t0, t1);
    if (tm > m) {
      float sc = __expf(m - tm);
      m = tm; den *= sc;
#pragma unroll
      for (int j = 0; j < 8; ++j) acc[j] *= sc;
    }
    float e0 = __expf(t0 - m), e1 = __expf(t1 - m);
    den += e0 + e1;
#pragma unroll
    for (int j = 0; j < 8; ++j) acc[j] += e0 * x0[j] + e1 * x1[j];
  }
  if (i < b) {
    unsigned pr = epack[i];
    int sn = (int)(pr & 0xFFFFu);
    float av = b2f((unsigned short)(pr >> 16));
    uint2 u = *(const uint2*)(const void*)(xl8 + (size_t)sn * 64 + c0);
    float x[8];
    f32x2 da = __builtin_amdgcn_cvt_pk_f32_fp8(u.x, false);
    f32x2 db = __builtin_amdgcn_cvt_pk_f32_fp8(u.x, true);
    f32x2 dc = __builtin_amdgcn_cvt_pk_f32_fp8(u.y, false);
    f32x2 dd = __builtin_amdgcn_cvt_pk_f32_fp8(u.y, true);
    x[0] = da[0]; x[1] = da[1]; x[2] = db[0]; x[3] = db[1];
    x[4] = dc[0]; x[5] = dc[1]; x[6] = dd[0]; x[7] = dd[1];
    float t = 0.f;
#pragma unroll
    for (int j = 0; j < 8; ++j) {
      float v = x[j] + xrf[j] + av * Wev[j];
      v = v > 0.f ? v : 0.2f * v;
      t += atv[j] * v;
    }
    t += __shfl_xor(t, 1, 8);
    t += __shfl_xor(t, 2, 8);
    t += __shfl_xor(t, 4, 8);
    if (t > m) {
      float sc = __expf(m - t);
      m = t; den *= sc;
#pragma unroll
      for (int j = 0; j < 8; ++j) acc[j] *= sc;
    }
    float ex = __expf(t - m);
    den += ex;
#pragma unroll
    for (int j = 0; j < 8; ++j) acc[j] += ex * x[j];
  }
  float inv = 1.f / (den + 1e-16f);
  float4 Ba = *(const float4*)(bias + c0), Bb = *(const float4*)(bias + c0 + 4);
  float bv[8] = {Ba.x, Ba.y, Ba.z, Ba.w, Bb.x, Bb.y, Bb.z, Bb.w};
  float vals[8];
#pragma unroll
  for (int j = 0; j < 8; ++j)
    vals[j] = valid ? fmaxf(acc[j] * inv + bv[j], 0.f) : 0.f;
#pragma unroll
  for (int j = 0; j < 8; ++j) {
    float v = vals[j];
    v += __shfl_xor(v, 8, 64);
    v += __shfl_xor(v, 16, 64);
    v += __shfl_xor(v, 32, 64);
    vals[j] = v;
  }
  if (lane < 8) {
#pragma unroll
    for (int j = 0; j < 8; ++j) gred[w][lane * 8 + j] = vals[j];
  }
  __syncthreads();
  if (tid < 64)
    atomicAdd(&g_sum[tid], gred[0][tid] + gred[1][tid] + gred[2][tid] + gred[3][tid]);
}

// ------- masked logits + exp, 2 rows per 4-lane group (ILP), gsum spread -------
__global__ __launch_bounds__(256) void k_logits(const float* __restrict__ g_sum,
    const float* __restrict__ Wp, const float* __restrict__ bp,
    const float* __restrict__ alpha,
    const float* __restrict__ Wf, const float* __restrict__ bf,
    const unsigned char* __restrict__ aflag, const int* __restrict__ src,
    const int* __restrict__ dst, float* __restrict__ exps,
    float* __restrict__ gsum, float* __restrict__ out,
    int E, int NA, float invN) {
  __shared__ float gs[64];
  __shared__ float wsum[4];
  int tid = threadIdx.x;
  if (tid < 64) gs[tid] = g_sum[tid] * invN;
  __syncthreads();
  if (blockIdx.x == 0 && tid < 64) {
    float t = wred_sum(gs[tid] * Wp[tid]);
    if (tid == 0) {
      float sp = t + bp[0];
      out[NA] = sp > 0.f ? sp : 0.f;
      out[NA + 1] = 1.f / (1.f + __expf(-alpha[0]));
    }
  }
  int j0 = tid & 3;
  int row0 = blockIdx.x * 128 + (tid >> 2);
  int row1 = row0 + 64;
  const float4* g4 = (const float4*)gs;
  float4 gva = g4[j0], gvb = g4[j0 + 4], gvc = g4[j0 + 8], gvd = g4[j0 + 12];
  float ex0 = 0.f, ex1 = 0.f;
  bool r0ok = row0 < NA, r1ok = row1 < NA;
  float acc0 = 0.f, acc1 = 0.f;
  if (r0ok) {
    const float4* wr = (const float4*)(Wf + (size_t)row0 * 64);
    float4 w0 = wr[j0], w1 = wr[j0 + 4], w2 = wr[j0 + 8], w3 = wr[j0 + 12];
    acc0 = w0.x * gva.x + w0.y * gva.y + w0.z * gva.z + w0.w * gva.w
         + w1.x * gvb.x + w1.y * gvb.y + w1.z * gvb.z + w1.w * gvb.w
         + w2.x * gvc.x + w2.y * gvc.y + w2.z * gvc.z + w2.w * gvc.w
         + w3.x * gvd.x + w3.y * gvd.y + w3.z * gvd.z + w3.w * gvd.w;
  }
  if (r1ok) {
    const float4* wr = (const float4*)(Wf + (size_t)row1 * 64);
    float4 w0 = wr[j0], w1 = wr[j0 + 4], w2 = wr[j0 + 8], w3 = wr[j0 + 12];
    acc1 = w0.x * gva.x + w0.y * gva.y + w0.z * gva.z + w0.w * gva.w
         + w1.x * gvb.x + w1.y * gvb.y + w1.z * gvb.z + w1.w * gvb.w
         + w2.x * gvc.x + w2.y * gvc.y + w2.z * gvc.z + w2.w * gvc.w
         + w3.x * gvd.x + w3.y * gvd.y + w3.z * gvd.z + w3.w * gvd.w;
  }
  acc0 += __shfl_xor(acc0, 1, 4); acc1 += __shfl_xor(acc1, 1, 4);
  acc0 += __shfl_xor(acc0, 2, 4); acc1 += __shfl_xor(acc1, 2, 4);
  if (j0 == 0) {
    if (r0ok) {
      bool keep = (!aflag[row0]) && (row0 >= E || src[row0] != dst[row0]);
      ex0 = keep ? __expf(acc0 + bf[row0]) : 0.f;
      exps[row0] = ex0;
    }
    if (r1ok) {
      bool keep = (!aflag[row1]) && (row1 >= E || src[row1] != dst[row1]);
      ex1 = keep ? __expf(acc1 + bf[row1]) : 0.f;
      exps[row1] = ex1;
    }
  }
  float s = wred_sum(ex0 + ex1);
  if ((tid & 63) == 0) wsum[tid >> 6] = s;
  __syncthreads();
  if (tid == 0)
    atomicAdd(&gsum[blockIdx.x & 63],
              wsum[0] + wsum[1] + wsum[2] + wsum[3]);
}

// ---------------- norm: reduce 64 gsum slots in-wave, then scale ---------------
__global__ __launch_bounds__(256) void k_norm(const float* __restrict__ exps,
    const float* __restrict__ gsum, float* __restrict__ out, int NA) {
  int tid = threadIdx.x;
  float total = gsum[tid & 63];
  total = wred_sum(total);
  float inv = 1.f / total;
  int i = (blockIdx.x * 256 + tid) * 4;
  if (i >= NA) return;
  if (i + 3 < NA) {
    float4 v = *(const float4*)(exps + i);
    float4 o;
    o.x = v.x * inv; o.y = v.y * inv; o.z = v.z * inv; o.w = v.w * inv;
    *(float4*)(out + i) = o;
  } else {
    for (int j = i; j < NA; ++j) out[j] = exps[j] * inv;
  }
}

// ---------------- launch ----------------
extern "C" void kernel_launch(void* const* d_in, const int* in_sizes, int n_in,
                              void* d_out, int out_size, void* d_ws, size_t ws_size,
                              hipStream_t stream) {
  const float* x      = (const float*)d_in[0];
  const int*   eidx   = (const int*)d_in[1];
  const float* eattr  = (const float*)d_in[2];
  const int*   actions= (const int*)d_in[3];
  const float* Wl1 = (const float*)d_in[4];
  const float* bl1 = (const float*)d_in[5];
  const float* Wr1 = (const float*)d_in[6];
  const float* br1 = (const float*)d_in[7];
  const float* We1 = (const float*)d_in[8];
  const float* att1= (const float*)d_in[9];
  const float* bias1=(const float*)d_in[10];
  const float* Wl2 = (const float*)d_in[11];
  const float* bl2 = (const float*)d_in[12];
  const float* Wr2 = (const float*)d_in[13];
  const float* br2 = (const float*)d_in[14];
  const float* We2 = (const float*)d_in[15];
  const float* att2= (const float*)d_in[16];
  const float* bias2=(const float*)d_in[17];
  const float* Wf  = (const float*)d_in[18];
  const float* bf  = (const float*)d_in[19];
  const float* Wp  = (const float*)d_in[20];
  const float* bp  = (const float*)d_in[21];
  const float* alpha=(const float*)d_in[22];

  const int F = 128;
  const int N = in_sizes[0] / F;       // 20000
  const int E = in_sizes[2];           // 400000
  const int E2 = E + N;
  const int NA = E + 1;
  const int n_act = in_sizes[3];
  const int* src = eidx;
  const int* dst = eidx + E;

  float* ws = (float*)d_ws;
  size_t p = 0;
  int*      cnt_i    = (int*)(ws + p);      p += (size_t)N;
  float*    sum_ea   = ws + p;              p += (size_t)N;
  float*    g_sum    = ws + p;              p += 64;
  float*    gsum     = ws + p;              p += 64;
  unsigned char* aflag = (unsigned char*)(ws + p); p += ((size_t)NA + 3) / 4;
  size_t zero_bytes = p * sizeof(float);
  int*      row_st   = (int*)(ws + p);      p += (size_t)N + 64;
  int*      rank     = (int*)(ws + p);      p += (size_t)E;
  unsigned* epack    = (unsigned*)(ws + p); p += (size_t)E2;
  float*    exps     = ws + p;              p += (size_t)NA + 64;
  unsigned char* xl8 = (unsigned char*)(ws + p); p += (size_t)N * 256 / 4;
  unsigned char* xl28 = (unsigned char*)(ws + p); p += (size_t)N * 64 / 4;
  ushort* ub = (ushort*)(ws + p);
  size_t q = 0;
  ushort* xb   = ub + q; q += (size_t)N * F;
  ushort* wl1b = ub + q; q += (size_t)256 * 128;
  ushort* wr1b = ub + q; q += (size_t)256 * 128;
  ushort* wl2b = ub + q; q += (size_t)64 * 256;
  ushort* wr2b = ub + q; q += (size_t)64 * 256;
  ushort* xr1b = ub + q; q += (size_t)N * 256;
  ushort* h1b  = ub + q; q += (size_t)N * 256;
  ushort* xr2b = ub + q; q += (size_t)N * 64;

  float* out = (float*)d_out;

  hipMemsetAsync(d_ws, 0, zero_bytes, stream);

  // prep: casts + degree count (rank capture) + aflag, one launch
  {
    int n0 = N * F, n1 = 256 * 128, n2 = 256 * 128, n3 = 64 * 256, n4 = 64 * 256;
    int tot4 = (n0 + n1 + n2 + n3 + n4) / 4;
    int castB = (tot4 + 255) / 256;
    int cntB = (E + 255) / 256;
    k_prep<<<castB + cntB, 256, 0, stream>>>(
        x, xb, n0, Wl1, wl1b, n1, Wr1, wr1b, n2, Wl2, wl2b, n3, Wr2, wr2b, n4,
        dst, eattr, cnt_i, sum_ea, rank, E, actions, aflag, n_act, castB);
  }

  k_scan<<<1, 1024, 0, stream>>>(cnt_i, row_st, N);

  // layer-1 GEMMs (fp8 xl out) + atomic-free CSR scatter in one launch
  {
    dim3 g1((N + 63) / 64, 4, 3);
    k_gemm_scatter<<<g1, 256, 0, stream>>>(xb, wl1b, bl1, xl8, wr1b, br1, xr1b,
                                           N, 256, 128,
                                           dst, src, eattr, cnt_i, sum_ea,
                                           rank, row_st, epack, E, E2);
  }
  k_fused1<<<(N + 7) / 8, 256, 0, stream>>>(xl8, xr1b, epack, row_st,
                                            We1, att1, bias1, h1b, N);
  {
    dim3 g2((N + 63) / 64, 1, 2);
    k_gemm_mfma2<<<g2, 256, 0, stream>>>(h1b, wl2b, bl2, xl28, wr2b, br2, xr2b,
                                         N, 64, 256);
  }
  k_fused2<<<(N + 31) / 32, 256, 0, stream>>>(xl28, xr2b, epack, row_st,
                                              We2, att2, bias2, g_sum, N);

  k_logits<<<(NA + 127) / 128, 256, 0, stream>>>(
      g_sum, Wp, bp, alpha, Wf, bf, aflag, src, dst,
      exps, gsum, out, E, NA, 1.0f / (float)N);
  int nb4 = (NA + 1023) / 1024;
  k_norm<<<nb4, 256, 0, stream>>>(exps, gsum, out, NA);
}